// Round 5
// baseline (51.504 us; speedup 1.0000x reference)
//
#include <hip/hip_runtime.h>

#define N_SPK 1024
#define M_UTT 16
#define D_DIM 512

typedef __attribute__((ext_vector_type(8))) short bf16x8;
typedef __attribute__((ext_vector_type(4))) float f32x4;

__device__ __forceinline__ float wave_sum64(float v) {
  #pragma unroll
  for (int off = 32; off >= 1; off >>= 1) v += __shfl_xor(v, off, 64);
  return v;
}

__device__ __forceinline__ unsigned short f2bf(float x) {
  unsigned int u = __float_as_uint(x);
  unsigned int r = (u + 0x7FFFu + ((u >> 16) & 1u)) >> 16;  // RNE
  return (unsigned short)r;
}

__device__ __forceinline__ unsigned int pack_bf16(float a, float b) {
  return (unsigned int)f2bf(a) | ((unsigned int)f2bf(b) << 16);
}

__device__ __forceinline__ void gload_lds16(const void* g, void* l) {
  __builtin_amdgcn_global_load_lds(
      (const __attribute__((address_space(1))) void*)g,
      (__attribute__((address_space(3))) void*)l, 16, 0, 0);
}

// Kernel 1: per speaker n — centroid unit vec (bf16), normalized embeddings
// (bf16), and the exact fp32 leave-one-out diagonal logit pos = w*(diag+eps)+b.
__global__ __launch_bounds__(256) void prep_kernel(
    const float* __restrict__ emb, const float* __restrict__ wp,
    const float* __restrict__ bp, unsigned int* __restrict__ eU,
    unsigned int* __restrict__ cU, float* __restrict__ pos_out)
{
  const int n = blockIdx.x;
  const int t = threadIdx.x;
  __shared__ float es[M_UTT * D_DIM];
  __shared__ float Sd[D_DIM];
  __shared__ float red[4];
  __shared__ float inv_s[M_UTT];

  const float* base = emb + (size_t)n * (M_UTT * D_DIM);
  #pragma unroll
  for (int i = 0; i < 8; ++i) {
    int s = t + i * 256;
    reinterpret_cast<float4*>(es)[s] = reinterpret_cast<const float4*>(base)[s];
  }
  __syncthreads();

  #pragma unroll
  for (int rep = 0; rep < 2; ++rep) {
    int d = t + rep * 256;
    float s = 0.f;
    #pragma unroll
    for (int m = 0; m < M_UTT; ++m) s += es[m * D_DIM + d];
    Sd[d] = s;
  }
  __syncthreads();

  float p = 0.f;
  #pragma unroll
  for (int rep = 0; rep < 2; ++rep) {
    int d = t + rep * 256;
    float c = Sd[d] * (1.f / M_UTT);
    p += c * c;
  }
  p = wave_sum64(p);
  if ((t & 63) == 0) red[t >> 6] = p;
  __syncthreads();
  float cn2 = red[0] + red[1] + red[2] + red[3];
  float invc = 1.f / fmaxf(sqrtf(cn2), 1e-8f);

  // centroid unit vector -> bf16 (2 elems per thread)
  {
    int d = t * 2;
    float c0 = Sd[d] * (1.f / M_UTT) * invc;
    float c1 = Sd[d + 1] * (1.f / M_UTT) * invc;
    cU[n * 256 + t] = pack_bf16(c0, c1);
  }

  // per-m diag (exact fp32) + inverse norms
  const int wid = t >> 6, lane = t & 63;
  const float w = *wp, b = *bp;
  for (int m = wid; m < M_UTT; m += 4) {
    float dot = 0.f, ne = 0.f, nl = 0.f;
    #pragma unroll
    for (int r = 0; r < 8; ++r) {
      int d = lane + r * 64;
      float e = es[m * D_DIM + d];
      float l = Sd[d] - e;
      dot += e * l; ne += e * e; nl += l * l;
    }
    dot = wave_sum64(dot); ne = wave_sum64(ne); nl = wave_sum64(nl);
    if (lane == 0) {
      float inv_e = 1.f / fmaxf(sqrtf(ne), 1e-8f);
      float inv_l = 1.f / fmaxf(sqrtf(nl) * (1.f / (M_UTT - 1)), 1e-8f);
      float diag = dot * (1.f / (M_UTT - 1)) * inv_e * inv_l;
      pos_out[n * M_UTT + m] = w * (diag + 1e-6f) + b;
      inv_s[m] = inv_e;
    }
  }
  __syncthreads();

  // normalized embeddings -> bf16 (16 iters x 2 elems)
  #pragma unroll
  for (int i = 0; i < 16; ++i) {
    int p2 = t + i * 256;            // pair index 0..4095
    int m = p2 >> 8;
    int d = (p2 & 255) * 2;
    float sc = inv_s[m];
    float x0 = es[m * D_DIM + d] * sc;
    float x1 = es[m * D_DIM + d + 1] * sc;
    eU[(size_t)n * 4096 + p2] = pack_bf16(x0, x1);
  }
}

// Kernel 2: bf16 MFMA GEMM (16384x1024x512) with fused exp epilogue.
// 128x128 block tile, BK=64, 4 waves (2x2), 64x64 per wave, 4x4 fragments.
// A/B staged via global_load_lds(16B) with pre-swizzled source; ds_read_b128
// with matching XOR swizzle (seg ^= row&7).
#define BM 128
#define BN 128
#define BK 64

__global__ __launch_bounds__(256) void mfma_kernel(
    const unsigned short* __restrict__ eU, const unsigned short* __restrict__ cU,
    const float* __restrict__ pos, const float* __restrict__ wp,
    const float* __restrict__ bp, float* __restrict__ partial)
{
  __shared__ unsigned short As[BM * BK];
  __shared__ unsigned short Bs[BN * BK];
  __shared__ float rowsum[2][BM];
  __shared__ float pos_l[BM];

  const int t = threadIdx.x;
  const int lane = t & 63;
  const int wv_id = t >> 6;            // 0..3
  const int wm = wv_id >> 1, wn = wv_id & 1;
  const int cb = blockIdx.x, rb = blockIdx.y;
  const int row0 = rb * BM, col0 = cb * BN;

  if (t < BM) pos_l[t] = pos[row0 + t];

  const float w = *wp, b = *bp;
  const float bb = w * 1e-6f + b;      // fold +SIM_EPS

  f32x4 acc[4][4] = {};

  const int lrow = lane >> 3;              // row within 8-row chunk
  const int lseg = (lane & 7) ^ lrow;      // pre-swizzled 16B-seg in source

  for (int kt = 0; kt < D_DIM / BK; ++kt) {
    const int d0 = kt * BK;
    __syncthreads();
    #pragma unroll
    for (int i = 0; i < 4; ++i) {
      int c = wv_id * 4 + i;               // chunk 0..15 (8 rows each)
      size_t gr = (size_t)(row0 + c * 8 + lrow) * D_DIM + d0 + lseg * 8;
      gload_lds16(eU + gr, (char*)As + c * 1024);
      size_t gc = (size_t)(col0 + c * 8 + lrow) * D_DIM + d0 + lseg * 8;
      gload_lds16(cU + gc, (char*)Bs + c * 1024);
    }
    __syncthreads();   // compiler drains vmcnt before barrier

    #pragma unroll
    for (int kk = 0; kk < 2; ++kk) {
      bf16x8 af[4], bf[4];
      #pragma unroll
      for (int mi = 0; mi < 4; ++mi) {
        int r = wm * 64 + mi * 16 + (lane & 15);
        int seg = ((lane >> 4) + kk * 4) ^ (r & 7);
        af[mi] = *reinterpret_cast<const bf16x8*>(
            (const char*)As + r * 128 + seg * 16);
      }
      #pragma unroll
      for (int nj = 0; nj < 4; ++nj) {
        int s = wn * 64 + nj * 16 + (lane & 15);
        int seg = ((lane >> 4) + kk * 4) ^ (s & 7);
        bf[nj] = *reinterpret_cast<const bf16x8*>(
            (const char*)Bs + s * 128 + seg * 16);
      }
      #pragma unroll
      for (int mi = 0; mi < 4; ++mi)
        #pragma unroll
        for (int nj = 0; nj < 4; ++nj)
          acc[mi][nj] = __builtin_amdgcn_mfma_f32_16x16x32_bf16(
              af[mi], bf[nj], acc[mi][nj], 0, 0, 0);
    }
  }

  // fused epilogue: arg = w*acc + bb (diag -> pos), exp, per-row sums
  float esum[4][4];
  #pragma unroll
  for (int mi = 0; mi < 4; ++mi)
    #pragma unroll
    for (int rg = 0; rg < 4; ++rg) esum[mi][rg] = 0.f;

  #pragma unroll
  for (int nj = 0; nj < 4; ++nj) {
    int kg = col0 + wn * 64 + nj * 16 + (lane & 15);
    #pragma unroll
    for (int mi = 0; mi < 4; ++mi) {
      #pragma unroll
      for (int rg = 0; rg < 4; ++rg) {
        int r_loc = wm * 64 + mi * 16 + (lane >> 4) * 4 + rg;
        float arg = w * acc[mi][nj][rg] + bb;
        if (kg == ((row0 + r_loc) >> 4)) arg = pos_l[r_loc];
        esum[mi][rg] += __expf(arg);
      }
    }
  }
  // reduce across the 16 column-lanes (same rows: lane bits 0-3)
  #pragma unroll
  for (int mi = 0; mi < 4; ++mi)
    #pragma unroll
    for (int rg = 0; rg < 4; ++rg) {
      float v = esum[mi][rg];
      v += __shfl_xor(v, 1, 64);
      v += __shfl_xor(v, 2, 64);
      v += __shfl_xor(v, 4, 64);
      v += __shfl_xor(v, 8, 64);
      esum[mi][rg] = v;
    }
  if ((lane & 15) == 0) {
    #pragma unroll
    for (int mi = 0; mi < 4; ++mi)
      #pragma unroll
      for (int rg = 0; rg < 4; ++rg)
        rowsum[wn][wm * 64 + mi * 16 + (lane >> 4) * 4 + rg] = esum[mi][rg];
  }
  __syncthreads();
  if (t < BM) partial[(size_t)cb * (N_SPK * M_UTT) + row0 + t] =
      rowsum[0][t] + rowsum[1][t];
}

__global__ __launch_bounds__(256) void finalize_kernel(
    const float* __restrict__ partial, const float* __restrict__ pos,
    float* __restrict__ bsum)
{
  const int t = threadIdx.x;
  const int r = blockIdx.x * 256 + t;
  float s = 0.f;
  #pragma unroll
  for (int cb = 0; cb < 8; ++cb) s += partial[cb * (N_SPK * M_UTT) + r];
  float v = logf(s + 1e-6f) - pos[r];
  v = wave_sum64(v);
  __shared__ float red[4];
  if ((t & 63) == 0) red[t >> 6] = v;
  __syncthreads();
  if (t == 0) bsum[blockIdx.x] = red[0] + red[1] + red[2] + red[3];
}

__global__ void final_reduce(const float* __restrict__ bsum,
                             float* __restrict__ out)
{
  float v = bsum[threadIdx.x];
  v = wave_sum64(v);
  if (threadIdx.x == 0) out[0] = v;
}

extern "C" void kernel_launch(void* const* d_in, const int* in_sizes, int n_in,
                              void* d_out, int out_size, void* d_ws, size_t ws_size,
                              hipStream_t stream) {
  const float* emb = (const float*)d_in[0];
  const float* wp  = (const float*)d_in[1];
  const float* bp  = (const float*)d_in[2];
  float* out = (float*)d_out;

  char* wsb = (char*)d_ws;
  unsigned int* eU  = (unsigned int*)wsb;                       // 16,777,216 B
  unsigned int* cU  = (unsigned int*)(wsb + 16777216);          //  1,048,576 B
  float* pos        = (float*)(wsb + 16777216 + 1048576);       //     65,536 B
  float* partial    = (float*)(wsb + 16777216 + 1048576 + 65536);   // 524,288 B
  float* bsum       = (float*)(wsb + 16777216 + 1048576 + 65536 + 524288);

  prep_kernel<<<N_SPK, 256, 0, stream>>>(emb, wp, bp, eU, cU, pos);
  dim3 grid(N_SPK / BN, (N_SPK * M_UTT) / BM);
  mfma_kernel<<<grid, 256, 0, stream>>>(
      (const unsigned short*)eU, (const unsigned short*)cU, pos, wp, bp, partial);
  finalize_kernel<<<(N_SPK * M_UTT) / 256, 256, 0, stream>>>(partial, pos, bsum);
  final_reduce<<<1, 64, 0, stream>>>(bsum, out);
}

// Round 6
// 45.670 us; speedup vs baseline: 1.1277x; 1.1277x over previous
//
#include <hip/hip_runtime.h>

#define N_SPK 1024
#define M_UTT 16
#define D_DIM 512

typedef __attribute__((ext_vector_type(8))) short bf16x8;
typedef __attribute__((ext_vector_type(4))) float f32x4;

__device__ __forceinline__ float wave_sum64(float v) {
  #pragma unroll
  for (int off = 32; off >= 1; off >>= 1) v += __shfl_xor(v, off, 64);
  return v;
}

__device__ __forceinline__ unsigned short f2bf(float x) {
  unsigned int u = __float_as_uint(x);
  unsigned int r = (u + 0x7FFFu + ((u >> 16) & 1u)) >> 16;  // RNE
  return (unsigned short)r;
}

__device__ __forceinline__ unsigned int pack_bf16(float a, float b) {
  return (unsigned int)f2bf(a) | ((unsigned int)f2bf(b) << 16);
}

__device__ __forceinline__ void gload_lds16(const void* g, void* l) {
  __builtin_amdgcn_global_load_lds(
      (const __attribute__((address_space(1))) void*)g,
      (__attribute__((address_space(3))) void*)l, 16, 0, 0);
}

// Kernel 1: per speaker n — centroid unit vec (bf16), normalized embeddings
// (bf16), exact fp32 LOO diagonal logit pos = w*(diag+eps)+b.  (unchanged)
__global__ __launch_bounds__(256) void prep_kernel(
    const float* __restrict__ emb, const float* __restrict__ wp,
    const float* __restrict__ bp, unsigned int* __restrict__ eU,
    unsigned int* __restrict__ cU, float* __restrict__ pos_out)
{
  const int n = blockIdx.x;
  const int t = threadIdx.x;
  __shared__ float es[M_UTT * D_DIM];
  __shared__ float Sd[D_DIM];
  __shared__ float red[4];
  __shared__ float inv_s[M_UTT];

  const float* base = emb + (size_t)n * (M_UTT * D_DIM);
  #pragma unroll
  for (int i = 0; i < 8; ++i) {
    int s = t + i * 256;
    reinterpret_cast<float4*>(es)[s] = reinterpret_cast<const float4*>(base)[s];
  }
  __syncthreads();

  #pragma unroll
  for (int rep = 0; rep < 2; ++rep) {
    int d = t + rep * 256;
    float s = 0.f;
    #pragma unroll
    for (int m = 0; m < M_UTT; ++m) s += es[m * D_DIM + d];
    Sd[d] = s;
  }
  __syncthreads();

  float p = 0.f;
  #pragma unroll
  for (int rep = 0; rep < 2; ++rep) {
    int d = t + rep * 256;
    float c = Sd[d] * (1.f / M_UTT);
    p += c * c;
  }
  p = wave_sum64(p);
  if ((t & 63) == 0) red[t >> 6] = p;
  __syncthreads();
  float cn2 = red[0] + red[1] + red[2] + red[3];
  float invc = 1.f / fmaxf(sqrtf(cn2), 1e-8f);

  {
    int d = t * 2;
    float c0 = Sd[d] * (1.f / M_UTT) * invc;
    float c1 = Sd[d + 1] * (1.f / M_UTT) * invc;
    cU[n * 256 + t] = pack_bf16(c0, c1);
  }

  const int wid = t >> 6, lane = t & 63;
  const float w = *wp, b = *bp;
  for (int m = wid; m < M_UTT; m += 4) {
    float dot = 0.f, ne = 0.f, nl = 0.f;
    #pragma unroll
    for (int r = 0; r < 8; ++r) {
      int d = lane + r * 64;
      float e = es[m * D_DIM + d];
      float l = Sd[d] - e;
      dot += e * l; ne += e * e; nl += l * l;
    }
    dot = wave_sum64(dot); ne = wave_sum64(ne); nl = wave_sum64(nl);
    if (lane == 0) {
      float inv_e = 1.f / fmaxf(sqrtf(ne), 1e-8f);
      float inv_l = 1.f / fmaxf(sqrtf(nl) * (1.f / (M_UTT - 1)), 1e-8f);
      float diag = dot * (1.f / (M_UTT - 1)) * inv_e * inv_l;
      pos_out[n * M_UTT + m] = w * (diag + 1e-6f) + b;
      inv_s[m] = inv_e;
    }
  }
  __syncthreads();

  #pragma unroll
  for (int i = 0; i < 16; ++i) {
    int p2 = t + i * 256;
    int m = p2 >> 8;
    int d = (p2 & 255) * 2;
    float sc = inv_s[m];
    float x0 = es[m * D_DIM + d] * sc;
    float x1 = es[m * D_DIM + d + 1] * sc;
    eU[(size_t)n * 4096 + p2] = pack_bf16(x0, x1);
  }
}

// Kernel 2: 256x256 tile, BK=32, 8 waves (2x4), ring-of-4 LDS buffers,
// counted vmcnt pipeline (depth 3), row-pair XOR swizzle, fused exp epilogue.
// LDS: A bufs [0,64K), B bufs [64K,128K). Each buf: 256 rows x 32 k bf16 = 16KB,
// stored as [rowpair][seg' = ((p*4+kseg) ^ (rowpair&7))*16B].
#define NTILES 16   // 512 / 32

struct StageOff { unsigned int gA0, gA1, gB0, gB1; int c0off, c1off; };

__device__ __forceinline__ void stage_tile(
    const char* __restrict__ eU, const char* __restrict__ cU,
    char* AsB, int t, const StageOff& so)
{
  const int buf = t & 3;
  const int d0b = t * 64;                 // 32 k-elems * 2B
  char* Ab = AsB + buf * 16384;
  char* Bb = AsB + 65536 + buf * 16384;
  gload_lds16(eU + so.gA0 + d0b, Ab + so.c0off);
  gload_lds16(eU + so.gA1 + d0b, Ab + so.c1off);
  gload_lds16(cU + so.gB0 + d0b, Bb + so.c0off);
  gload_lds16(cU + so.gB1 + d0b, Bb + so.c1off);
}

__device__ __forceinline__ void compute_tile(
    const char* AsB, int t, int wm, int wn, int laneoff, f32x4 acc[8][4])
{
  const int buf = t & 3;
  const char* Ab = AsB + buf * 16384;
  const char* Bb = AsB + 65536 + buf * 16384;
  bf16x8 af[8], bfr[4];
  #pragma unroll
  for (int mi = 0; mi < 8; ++mi)
    af[mi] = *reinterpret_cast<const bf16x8*>(Ab + (wm * 128 + mi * 16) * 64 + laneoff);
  #pragma unroll
  for (int nj = 0; nj < 4; ++nj)
    bfr[nj] = *reinterpret_cast<const bf16x8*>(Bb + (wn * 64 + nj * 16) * 64 + laneoff);
  __builtin_amdgcn_s_setprio(1);
  #pragma unroll
  for (int mi = 0; mi < 8; ++mi)
    #pragma unroll
    for (int nj = 0; nj < 4; ++nj)
      acc[mi][nj] = __builtin_amdgcn_mfma_f32_16x16x32_bf16(
          af[mi], bfr[nj], acc[mi][nj], 0, 0, 0);
  __builtin_amdgcn_s_setprio(0);
}

__global__ __launch_bounds__(512, 2) void mfma_kernel(
    const char* __restrict__ eU, const char* __restrict__ cU,
    const float* __restrict__ pos, const float* __restrict__ wp,
    const float* __restrict__ bp, float* __restrict__ partial)
{
  __shared__ char AsB[131072];
  __shared__ float pos_l[256];
  __shared__ float rowsum[4][256];

  const int t = threadIdx.x;
  const int lane = t & 63;
  const int wv = t >> 6;               // 0..7
  const int wm = wv >> 2, wn = wv & 3;

  // XCD swizzle (256 blocks, 8 XCDs): cb varies fastest within an XCD chunk
  const int bid = blockIdx.x;
  const int sw = (bid & 7) * 32 + (bid >> 3);
  const int cb = sw & 3, rb = sw >> 2;
  const int row0 = rb * 256, col0 = cb * 256;

  const float w = *wp, b = *bp;        // uniform -> s_load (lgkm, not vmcnt)
  const float bb = w * 1e-6f + b;

  if (t < 256) pos_l[t] = pos[row0 + t];

  // per-thread staging offsets: chunk c covers rows 16c..16c+15 of the tile.
  // lane l writes LDS linear slot (rp_local = l>>3, s' = l&7); content is
  // global (row = 2*(c*8 + l>>3) + p, kseg) with seg = s'^rp_local.
  StageOff so;
  {
    const int seg = (lane & 7) ^ (lane >> 3);
    const int p = seg >> 2, ks = seg & 3;
    const int rA0 = ((2 * wv) * 8 + (lane >> 3)) * 2 + p;
    const int rA1 = ((2 * wv + 1) * 8 + (lane >> 3)) * 2 + p;
    so.gA0 = (unsigned int)(row0 + rA0) * 1024u + ks * 16;
    so.gA1 = (unsigned int)(row0 + rA1) * 1024u + ks * 16;
    so.gB0 = (unsigned int)(col0 + rA0) * 1024u + ks * 16;
    so.gB1 = (unsigned int)(col0 + rA1) * 1024u + ks * 16;
    so.c0off = (2 * wv) * 1024;
    so.c1off = (2 * wv + 1) * 1024;
  }
  // fragment read offset (per-lane constant): row j = lane&15, kchunk g = lane>>4
  const int j = lane & 15, g = lane >> 4;
  const int laneoff = (j >> 1) * 128 + ((((j & 1) * 4 + g) ^ (j >> 1)) * 16);

  f32x4 acc[8][4] = {};

  __syncthreads();   // pos_l visible + full vmcnt drain (exact counting after)

  stage_tile(eU, cU, AsB, 0, so);
  stage_tile(eU, cU, AsB, 1, so);
  stage_tile(eU, cU, AsB, 2, so);

  for (int tt = 0; tt < NTILES - 2; ++tt) {
    asm volatile("s_waitcnt vmcnt(8)" ::: "memory");   // oldest tile landed
    __builtin_amdgcn_s_barrier();                      // visible to all waves
    if (tt < NTILES - 3) stage_tile(eU, cU, AsB, tt + 3, so);
    compute_tile(AsB, tt, wm, wn, laneoff, acc);
    __builtin_amdgcn_s_barrier();                      // reads done before reuse
  }
  asm volatile("s_waitcnt vmcnt(4)" ::: "memory");
  __builtin_amdgcn_s_barrier();
  compute_tile(AsB, NTILES - 2, wm, wn, laneoff, acc);
  __builtin_amdgcn_s_barrier();
  asm volatile("s_waitcnt vmcnt(0)" ::: "memory");
  __builtin_amdgcn_s_barrier();
  compute_tile(AsB, NTILES - 1, wm, wn, laneoff, acc);

  // fused epilogue: arg = w*acc + bb (diag -> pos), exp, per-row sums
  float esum[8][4];
  #pragma unroll
  for (int mi = 0; mi < 8; ++mi)
    #pragma unroll
    for (int rg = 0; rg < 4; ++rg) esum[mi][rg] = 0.f;

  #pragma unroll
  for (int nj = 0; nj < 4; ++nj) {
    const int kg = col0 + wn * 64 + nj * 16 + (lane & 15);
    #pragma unroll
    for (int mi = 0; mi < 8; ++mi) {
      #pragma unroll
      for (int rg = 0; rg < 4; ++rg) {
        const int r_loc = wm * 128 + mi * 16 + (lane >> 4) * 4 + rg;
        float arg = w * acc[mi][nj][rg] + bb;
        if (kg == ((row0 + r_loc) >> 4)) arg = pos_l[r_loc];
        esum[mi][rg] += __expf(arg);
      }
    }
  }
  #pragma unroll
  for (int mi = 0; mi < 8; ++mi)
    #pragma unroll
    for (int rg = 0; rg < 4; ++rg) {
      float v = esum[mi][rg];
      v += __shfl_xor(v, 1, 64);
      v += __shfl_xor(v, 2, 64);
      v += __shfl_xor(v, 4, 64);
      v += __shfl_xor(v, 8, 64);
      esum[mi][rg] = v;
    }
  if ((lane & 15) == 0) {
    #pragma unroll
    for (int mi = 0; mi < 8; ++mi)
      #pragma unroll
      for (int rg = 0; rg < 4; ++rg)
        rowsum[wn][wm * 128 + mi * 16 + (lane >> 4) * 4 + rg] = esum[mi][rg];
  }
  __syncthreads();
  if (t < 256)
    partial[(size_t)cb * (N_SPK * M_UTT) + row0 + t] =
        rowsum[0][t] + rowsum[1][t] + rowsum[2][t] + rowsum[3][t];
}

__global__ __launch_bounds__(256) void finalize_kernel(
    const float* __restrict__ partial, const float* __restrict__ pos,
    float* __restrict__ bsum)
{
  const int t = threadIdx.x;
  const int r = blockIdx.x * 256 + t;
  float s = 0.f;
  #pragma unroll
  for (int cb = 0; cb < 4; ++cb) s += partial[cb * (N_SPK * M_UTT) + r];
  float v = logf(s + 1e-6f) - pos[r];
  v = wave_sum64(v);
  __shared__ float red[4];
  if ((t & 63) == 0) red[t >> 6] = v;
  __syncthreads();
  if (t == 0) bsum[blockIdx.x] = red[0] + red[1] + red[2] + red[3];
}

__global__ void final_reduce(const float* __restrict__ bsum,
                             float* __restrict__ out)
{
  float v = bsum[threadIdx.x];
  v = wave_sum64(v);
  if (threadIdx.x == 0) out[0] = v;
}

extern "C" void kernel_launch(void* const* d_in, const int* in_sizes, int n_in,
                              void* d_out, int out_size, void* d_ws, size_t ws_size,
                              hipStream_t stream) {
  const float* emb = (const float*)d_in[0];
  const float* wp  = (const float*)d_in[1];
  const float* bp  = (const float*)d_in[2];
  float* out = (float*)d_out;

  char* wsb = (char*)d_ws;
  unsigned int* eU  = (unsigned int*)wsb;                       // 16,777,216 B
  unsigned int* cU  = (unsigned int*)(wsb + 16777216);          //  1,048,576 B
  float* pos        = (float*)(wsb + 16777216 + 1048576);       //     65,536 B
  float* partial    = (float*)(wsb + 16777216 + 1048576 + 65536);   // 262,144 B
  float* bsum       = (float*)(wsb + 16777216 + 1048576 + 65536 + 262144);

  prep_kernel<<<N_SPK, 256, 0, stream>>>(emb, wp, bp, eU, cU, pos);
  mfma_kernel<<<256, 512, 0, stream>>>(
      (const char*)eU, (const char*)cU, pos, wp, bp, partial);
  finalize_kernel<<<(N_SPK * M_UTT) / 256, 256, 0, stream>>>(partial, pos, bsum);
  final_reduce<<<1, 64, 0, stream>>>(bsum, out);
}